// Round 2
// baseline (308.313 us; speedup 1.0000x reference)
//
#include <hip/hip_runtime.h>
#include <hip/hip_bf16.h>
#include <math.h>

#define BB 32
#define CC 128
#define TT 2048
#define NCH 384

typedef __attribute__((ext_vector_type(8))) short short8;
typedef __attribute__((ext_vector_type(4))) float floatx4;

// Static workspace (bf16 bit-patterns). Fully rewritten every call.
__device__ ushort g_q[(size_t)BB * TT * CC]; // [b][t][c-block swizzled], Q*scale
__device__ ushort g_k[(size_t)BB * TT * CC]; // [b][t][c-block swizzled]
__device__ ushort g_v[(size_t)BB * CC * TT]; // [b][c][t, 8-blocks swizzled within 64-groups]

__device__ __forceinline__ ushort f2bf(float f) {
    uint u = __float_as_uint(f);
    u += 0x7fffu + ((u >> 16) & 1u); // RNE
    return (ushort)(u >> 16);
}

// Pre-pass: transpose+scale+swizzle Q,K -> [b][t][c]; convert+swizzle V -> [b][c][t]
__global__ __launch_bounds__(256) void prepass_kernel(const float* __restrict__ qkv) {
    __shared__ float lds[64][132];
    const int b = blockIdx.y;
    const int t0 = blockIdx.x * 64;
    const int tid = threadIdx.x;

    for (int part = 0; part < 2; ++part) {
        // load [c][t] tile (coalesced over t), write transposed into lds[t][c]
        const int c = tid >> 1;
        const int tb = (tid & 1) * 32;
        const float* src = qkv + ((size_t)(b * NCH + part * CC + c)) * TT + t0 + tb;
#pragma unroll
        for (int k = 0; k < 8; k++) {
            float4 f = *(const float4*)(src + 4 * k);
            lds[tb + 4 * k + 0][c] = f.x;
            lds[tb + 4 * k + 1][c] = f.y;
            lds[tb + 4 * k + 2][c] = f.z;
            lds[tb + 4 * k + 3][c] = f.w;
        }
        __syncthreads();
        const float scale = (part == 0) ? 0.08838834764831845f : 1.0f;
        ushort* dst = (part == 0 ? g_q : g_k) + ((size_t)(b * TT + t0)) * CC;
#pragma unroll
        for (int p = 0; p < 4; p++) {
            int t = p * 16 + (tid >> 4);
            int x = tid & 15;         // stored c-block
            int cb = x ^ (t & 7);     // source c-block (XOR swizzle baked into ws)
            ushort tmp[8];
#pragma unroll
            for (int j = 0; j < 8; j++) tmp[j] = f2bf(lds[t][cb * 8 + j] * scale);
            *(uint4*)(dst + (size_t)t * CC + x * 8) = *(uint4*)tmp;
        }
        __syncthreads();
    }
    // V: convert, swizzle 8-wide t-blocks within each aligned 64-group by (c&7)
    {
        const int c = tid >> 1;
        const int tb = (tid & 1) * 32;
        const float* src = qkv + ((size_t)(b * NCH + 2 * CC + c)) * TT + t0 + tb;
        ushort* dst = g_v + ((size_t)(b * CC + c)) * TT + t0;
#pragma unroll
        for (int k = 0; k < 8; k++) {
            float4 f = *(const float4*)(src + 4 * k);
            int tt = tb + 4 * k;
            int blk = tt >> 3;
            int off = tt & 7; // 0 or 4
            int dblk = blk ^ (c & 7);
            ushort tmp[4] = {f2bf(f.x), f2bf(f.y), f2bf(f.z), f2bf(f.w)};
            *(uint2*)(dst + dblk * 8 + off) = *(uint2*)tmp;
        }
    }
}

// Flash attention: 4 waves, q-tile 64 (16 rows/wave), kv-tile 64.
// S^T = K^T*Q (swapped: lane owns one q column), O^T = V*P^T.
__global__ __launch_bounds__(256) void attn_kernel(float* __restrict__ out) {
    __shared__ ushort Qs[64][128];
    __shared__ ushort Ks[64][128];
    __shared__ ushort Vs[128][64];
    __shared__ ushort Ps[4][16][72];

    const int b = blockIdx.y;
    const int q0 = blockIdx.x * 64;
    const int tid = threadIdx.x;
    const int w = tid >> 6;
    const int l = tid & 63;
    const int g = l >> 4;
    const int ln = l & 15;

    // stage Q (linear copy; swizzle pre-baked in g_q)
    {
        const uint4* src = (const uint4*)(g_q + ((size_t)(b * TT + q0)) * CC);
        uint4* d = (uint4*)&Qs[0][0];
#pragma unroll
        for (int i = 0; i < 4; i++) d[i * 256 + tid] = src[i * 256 + tid];
    }

    floatx4 oacc[8];
#pragma unroll
    for (int i = 0; i < 8; i++) oacc[i] = (floatx4){0.f, 0.f, 0.f, 0.f};
    float m_run = -INFINITY;
    float l_run = 0.f;

    const int qt_loc = (w << 4) | ln; // local q row owned by this lane (as N-col)
    const int qswz = qt_loc & 7;

    for (int kt0 = 0; kt0 < TT; kt0 += 64) {
        __syncthreads();
        { // stage K tile (linear)
            const uint4* src = (const uint4*)(g_k + ((size_t)(b * TT + kt0)) * CC);
            uint4* d = (uint4*)&Ks[0][0];
#pragma unroll
            for (int i = 0; i < 4; i++) d[i * 256 + tid] = src[i * 256 + tid];
        }
        { // stage V tile: Vs[c][0..63] = g_v[b][c][kt0..kt0+63]   (full 128 c's!)
            const ushort* src = g_v + ((size_t)(b * CC)) * TT + kt0;
            uint4* d = (uint4*)&Vs[0][0];
#pragma unroll
            for (int i = 0; i < 4; i++) {
                int idx = i * 256 + tid;
                int c = idx >> 3, o = idx & 7;
                d[idx] = *(const uint4*)(src + (size_t)c * TT + o * 8);
            }
        }
        __syncthreads();

        // S^T tile: rows kt (64), col = own q. sacc[s]: kt = 16s + 4g + r
        floatx4 sacc[4];
#pragma unroll
        for (int s = 0; s < 4; s++) sacc[s] = (floatx4){0.f, 0.f, 0.f, 0.f};
#pragma unroll
        for (int ck = 0; ck < 4; ck++) {
            int cbq = (4 * ck + g) ^ qswz;
            short8 bq = *(const short8*)&Qs[qt_loc][cbq * 8];
#pragma unroll
            for (int s = 0; s < 4; s++) {
                int kt = 16 * s + ln;
                int cbk = (4 * ck + g) ^ (kt & 7);
                short8 ak = *(const short8*)&Ks[kt][cbk * 8];
                sacc[s] = __builtin_amdgcn_mfma_f32_16x16x32_bf16(ak, bq, sacc[s], 0, 0, 0);
            }
        }

        // online softmax — all state lane-private (lane owns q column)
        float vmax = -INFINITY;
#pragma unroll
        for (int s = 0; s < 4; s++)
            vmax = fmaxf(vmax, fmaxf(fmaxf(sacc[s].x, sacc[s].y), fmaxf(sacc[s].z, sacc[s].w)));
        vmax = fmaxf(vmax, __shfl_xor(vmax, 16));
        vmax = fmaxf(vmax, __shfl_xor(vmax, 32));
        float mnew = fmaxf(m_run, vmax);
        float alpha = __expf(m_run - mnew);
        float rs = 0.f;
#pragma unroll
        for (int s = 0; s < 4; s++) {
            float p0 = __expf(sacc[s].x - mnew);
            float p1 = __expf(sacc[s].y - mnew);
            float p2 = __expf(sacc[s].z - mnew);
            float p3 = __expf(sacc[s].w - mnew);
            rs += (p0 + p1) + (p2 + p3);
            uint lo = (uint)f2bf(p0) | ((uint)f2bf(p1) << 16);
            uint hi = (uint)f2bf(p2) | ((uint)f2bf(p3) << 16);
            // P[q=ln][kt=16s+4g+{0..3}] — conflict-free packed writes
            *(uint*)&Ps[w][ln][16 * s + 4 * g] = lo;
            *(uint*)&Ps[w][ln][16 * s + 4 * g + 2] = hi;
        }
        rs += __shfl_xor(rs, 16);
        rs += __shfl_xor(rs, 32);
        l_run = l_run * alpha + rs;
        m_run = mnew;
#pragma unroll
        for (int i = 0; i < 8; i++) {
            oacc[i].x *= alpha; oacc[i].y *= alpha;
            oacc[i].z *= alpha; oacc[i].w *= alpha;
        }

        // PV: O^T += V * P^T  (wave-private P; same-wave RAW handled by lgkmcnt)
#pragma unroll
        for (int kk = 0; kk < 2; kk++) {
            short8 bp = *(const short8*)&Ps[w][ln][32 * kk + 8 * g];
#pragma unroll
            for (int ms = 0; ms < 8; ms++) {
                int c = 16 * ms + ln;
                int y = (4 * kk + g) ^ (c & 7);
                short8 av = *(const short8*)&Vs[c][y * 8];
                oacc[ms] = __builtin_amdgcn_mfma_f32_16x16x32_bf16(av, bp, oacc[ms], 0, 0, 0);
            }
        }
    }

    // epilogue: out[b][c][q0 + qt_loc] = O^T / l
    float inv = 1.0f / l_run;
    float* op = out + ((size_t)(b * CC)) * TT + q0 + qt_loc;
#pragma unroll
    for (int ms = 0; ms < 8; ms++) {
#pragma unroll
        for (int r = 0; r < 4; r++) {
            int c = 16 * ms + 4 * g + r;
            op[(size_t)c * TT] = oacc[ms][r] * inv;
        }
    }
}

extern "C" void kernel_launch(void* const* d_in, const int* in_sizes, int n_in,
                              void* d_out, int out_size, void* d_ws, size_t ws_size,
                              hipStream_t stream) {
    (void)in_sizes; (void)n_in; (void)d_ws; (void)ws_size; (void)out_size;
    const float* qkv = (const float*)d_in[0];
    float* out = (float*)d_out;
    dim3 grid(32, 32), blk(256);
    hipLaunchKernelGGL(prepass_kernel, grid, blk, 0, stream, qkv);
    hipLaunchKernelGGL(attn_kernel, grid, blk, 0, stream, out);
}

// Round 5
// 302.628 us; speedup vs baseline: 1.0188x; 1.0188x over previous
//
#include <hip/hip_runtime.h>
#include <hip/hip_bf16.h>
#include <math.h>

#define BB 32
#define CC 128
#define TT 2048
#define NCH 384

typedef __attribute__((ext_vector_type(8))) short short8;
typedef __attribute__((ext_vector_type(4))) float floatx4;

// Static workspace (bf16 bit-patterns). Fully rewritten every call.
__device__ ushort g_q[(size_t)BB * TT * CC]; // [b][t][c-block swizzled], Q*scale*log2e
__device__ ushort g_k[(size_t)BB * TT * CC]; // [b][t][c-block swizzled]
__device__ ushort g_v[(size_t)BB * CC * TT]; // [b][c][t, 8-blocks swizzled within 64-groups]

__device__ __forceinline__ ushort f2bf(float f) {
    uint u = __float_as_uint(f);
    u += 0x7fffu + ((u >> 16) & 1u); // RNE
    return (ushort)(u >> 16);
}

// Pre-pass v2: fully-coalesced loads (8 lanes cover a 256B row segment),
// LDS f32 transpose tile (stride 133: 2-way write / 4-way read conflicts),
// dest-linear V path (both sides coalesced, swizzle in source index).
__global__ __launch_bounds__(256) void prepass_kernel(const float* __restrict__ qkv) {
    __shared__ float lds[64][133];
    const int b = blockIdx.y;
    const int t0 = blockIdx.x * 64;
    const int tid = threadIdx.x;
    const int u = tid >> 3; // 0..31: row within 32-row group
    const int j = tid & 7;  // 8-float t-chunk

    for (int part = 0; part < 2; ++part) {
        // log2(e)/sqrt(128) folded into Q so attn softmax runs in exp2 domain
        const float scale = (part == 0) ? 0.127517451f : 1.0f;
        float4 fa[4][2];
#pragma unroll
        for (int i = 0; i < 4; i++) {
            const float* src = qkv + ((size_t)(b * NCH + part * CC + i * 32 + u)) * TT + t0 + j * 8;
            fa[i][0] = *(const float4*)src;
            fa[i][1] = *(const float4*)(src + 4);
        }
        if (part) __syncthreads(); // protect prior phase-B reads
#pragma unroll
        for (int i = 0; i < 4; i++) {
            int c = i * 32 + u;
#pragma unroll
            for (int q = 0; q < 2; q++) {
                lds[j * 8 + q * 4 + 0][c] = fa[i][q].x;
                lds[j * 8 + q * 4 + 1][c] = fa[i][q].y;
                lds[j * 8 + q * 4 + 2][c] = fa[i][q].z;
                lds[j * 8 + q * 4 + 3][c] = fa[i][q].w;
            }
        }
        __syncthreads();
        ushort* dst = (part == 0 ? g_q : g_k) + ((size_t)(b * TT + t0)) * CC;
#pragma unroll
        for (int p = 0; p < 4; p++) {
            int t = p * 16 + (tid >> 4);
            int x = tid & 15;
            int cb = x ^ (t & 7); // XOR swizzle baked into ws layout
            ushort tmp[8];
#pragma unroll
            for (int jj = 0; jj < 8; jj++) tmp[jj] = f2bf(lds[t][cb * 8 + jj] * scale);
            *(uint4*)(dst + (size_t)t * CC + x * 8) = *(uint4*)tmp;
        }
    }
    // V: dest-linear; source t-block permuted (sb = db ^ (c&7)) within 256B rows
    {
        const float* vsrc = qkv + ((size_t)(b * NCH + 2 * CC)) * TT + t0;
        ushort* vdst = g_v + ((size_t)(b * CC)) * TT + t0;
#pragma unroll
        for (int i = 0; i < 4; i++) {
            int idx = i * 256 + tid;
            int c = idx >> 3, db = idx & 7, sb = db ^ (c & 7);
            const float* s = vsrc + (size_t)c * TT + sb * 8;
            float4 f0 = *(const float4*)s;
            float4 f1 = *(const float4*)(s + 4);
            ushort tmp[8] = {f2bf(f0.x), f2bf(f0.y), f2bf(f0.z), f2bf(f0.w),
                             f2bf(f1.x), f2bf(f1.y), f2bf(f1.z), f2bf(f1.w)};
            *(uint4*)(vdst + (size_t)c * TT + db * 8) = *(uint4*)tmp;
        }
    }
}

// Flash attention v2: 4 waves, q-tile 64 (16 q/wave), kv-tile 64.
// S^T = K^T*Q (lane owns one q column -> lane-private softmax state).
// Q frags hoisted to registers; Ps aliased into Qs (LDS 48KB -> 3 blocks/CU);
// defer-max rescale skip; exp2-domain softmax; cvt_pk P conversion.
__global__ __launch_bounds__(256) void attn_kernel(float* __restrict__ out) {
    __shared__ ushort Qs[64][128];
    __shared__ ushort Ks[64][128];
    __shared__ ushort Vs[128][64];
    ushort (*Ps)[16][72] = reinterpret_cast<ushort(*)[16][72]>(&Qs[0][0]);

    const int b = blockIdx.y;
    const int q0 = blockIdx.x * 64;
    const int tid = threadIdx.x;
    const int w = tid >> 6;
    const int l = tid & 63;
    const int g = l >> 4;
    const int ln = l & 15;
    const int qt_loc = (w << 4) | ln;
    const int qswz = qt_loc & 7;

    // stage Q once (linear copy; swizzle pre-baked), hoist frags to registers
    {
        const uint4* src = (const uint4*)(g_q + ((size_t)(b * TT + q0)) * CC);
        uint4* d = (uint4*)&Qs[0][0];
#pragma unroll
        for (int i = 0; i < 4; i++) d[i * 256 + tid] = src[i * 256 + tid];
    }
    __syncthreads();
    short8 qfrag[4];
#pragma unroll
    for (int ck = 0; ck < 4; ck++) {
        int cbq = (4 * ck + g) ^ qswz;
        qfrag[ck] = *(const short8*)&Qs[qt_loc][cbq * 8];
    }

    floatx4 oacc[8];
#pragma unroll
    for (int i = 0; i < 8; i++) oacc[i] = (floatx4){0.f, 0.f, 0.f, 0.f};
    float m_run = -INFINITY;
    float l_run = 0.f;

    for (int kt0 = 0; kt0 < TT; kt0 += 64) {
        __syncthreads();
        { // stage K tile (linear)
            const uint4* src = (const uint4*)(g_k + ((size_t)(b * TT + kt0)) * CC);
            uint4* d = (uint4*)&Ks[0][0];
#pragma unroll
            for (int i = 0; i < 4; i++) d[i * 256 + tid] = src[i * 256 + tid];
        }
        { // stage V tile
            const ushort* src = g_v + ((size_t)(b * CC)) * TT + kt0;
            uint4* d = (uint4*)&Vs[0][0];
#pragma unroll
            for (int i = 0; i < 4; i++) {
                int idx = i * 256 + tid;
                int c = idx >> 3, o = idx & 7;
                d[idx] = *(const uint4*)(src + (size_t)c * TT + o * 8);
            }
        }
        __syncthreads();

        // S^T tile: sacc[s] holds kt = 16s + 4g + r, col = own q
        floatx4 sacc[4];
#pragma unroll
        for (int s = 0; s < 4; s++) sacc[s] = (floatx4){0.f, 0.f, 0.f, 0.f};
#pragma unroll
        for (int ck = 0; ck < 4; ck++) {
#pragma unroll
            for (int s = 0; s < 4; s++) {
                int kt = 16 * s + ln;
                int cbk = (4 * ck + g) ^ (kt & 7);
                short8 ak = *(const short8*)&Ks[kt][cbk * 8];
                sacc[s] = __builtin_amdgcn_mfma_f32_16x16x32_bf16(ak, qfrag[ck], sacc[s], 0, 0, 0);
            }
        }

        // online softmax (exp2 domain), defer-max: skip rescale if max grew <= 8
        float vmax = -INFINITY;
#pragma unroll
        for (int s = 0; s < 4; s++)
            vmax = fmaxf(vmax, fmaxf(fmaxf(sacc[s].x, sacc[s].y), fmaxf(sacc[s].z, sacc[s].w)));
        vmax = fmaxf(vmax, __shfl_xor(vmax, 16));
        vmax = fmaxf(vmax, __shfl_xor(vmax, 32));
        if (!__all(vmax <= m_run + 8.0f)) {
            float mnew = fmaxf(m_run, vmax);
            float alpha = exp2f(m_run - mnew);
            l_run *= alpha;
#pragma unroll
            for (int i = 0; i < 8; i++) {
                oacc[i].x *= alpha; oacc[i].y *= alpha;
                oacc[i].z *= alpha; oacc[i].w *= alpha;
            }
            m_run = mnew;
        }
        float rs = 0.f;
#pragma unroll
        for (int s = 0; s < 4; s++) {
            float p0 = exp2f(sacc[s].x - m_run);
            float p1 = exp2f(sacc[s].y - m_run);
            float p2 = exp2f(sacc[s].z - m_run);
            float p3 = exp2f(sacc[s].w - m_run);
            rs += (p0 + p1) + (p2 + p3);
            __hip_bfloat162 lo = __float22bfloat162_rn(make_float2(p0, p1));
            __hip_bfloat162 hi = __float22bfloat162_rn(make_float2(p2, p3));
            *(__hip_bfloat162*)&Ps[w][ln][16 * s + 4 * g] = lo;
            *(__hip_bfloat162*)&Ps[w][ln][16 * s + 4 * g + 2] = hi;
        }
        rs += __shfl_xor(rs, 16);
        rs += __shfl_xor(rs, 32);
        l_run += rs;

        // PV: O^T += V * P^T (wave-private P; same-wave RAW via lgkmcnt)
#pragma unroll
        for (int kk = 0; kk < 2; kk++) {
            short8 bp = *(const short8*)&Ps[w][ln][32 * kk + 8 * g];
#pragma unroll
            for (int ms = 0; ms < 8; ms++) {
                int c = 16 * ms + ln;
                int y = (4 * kk + g) ^ (c & 7);
                short8 av = *(const short8*)&Vs[c][y * 8];
                oacc[ms] = __builtin_amdgcn_mfma_f32_16x16x32_bf16(av, bp, oacc[ms], 0, 0, 0);
            }
        }
    }

    // epilogue: out[b][c][q0 + qt_loc] = O^T / l
    float inv = 1.0f / l_run;
    float* op = out + ((size_t)(b * CC)) * TT + q0 + qt_loc;
#pragma unroll
    for (int ms = 0; ms < 8; ms++) {
#pragma unroll
        for (int r = 0; r < 4; r++) {
            int c = 16 * ms + 4 * g + r;
            op[(size_t)c * TT] = oacc[ms][r] * inv;
        }
    }
}

extern "C" void kernel_launch(void* const* d_in, const int* in_sizes, int n_in,
                              void* d_out, int out_size, void* d_ws, size_t ws_size,
                              hipStream_t stream) {
    (void)in_sizes; (void)n_in; (void)d_ws; (void)ws_size; (void)out_size;
    const float* qkv = (const float*)d_in[0];
    float* out = (float*)d_out;
    dim3 grid(32, 32), blk(256);
    hipLaunchKernelGGL(prepass_kernel, grid, blk, 0, stream, qkv);
    hipLaunchKernelGGL(attn_kernel, grid, blk, 0, stream, out);
}

// Round 8
// 291.064 us; speedup vs baseline: 1.0593x; 1.0397x over previous
//
#include <hip/hip_runtime.h>
#include <hip/hip_bf16.h>
#include <math.h>

#define BB 32
#define CC 128
#define TT 2048
#define NCH 384

typedef __attribute__((ext_vector_type(8))) short short8;
typedef __attribute__((ext_vector_type(16))) float floatx16;

// Static workspace (bf16 bit-patterns). Fully rewritten every call.
__device__ ushort g_q[(size_t)BB * TT * CC]; // [b][t][c granule x = cb ^ (t&15)], Q*scale*log2e
__device__ ushort g_k[(size_t)BB * TT * CC]; // [b][t][c granule x = cb ^ (t&15)]
__device__ ushort g_v[(size_t)BB * CC * TT]; // [b][c][t granule db = sb ^ (c&7) within 64-groups]

__device__ __forceinline__ ushort f2bf(float f) {
    uint u = __float_as_uint(f);
    u += 0x7fffu + ((u >> 16) & 1u); // RNE
    return (ushort)(u >> 16);
}

typedef __attribute__((address_space(1))) const unsigned char ga_t;
typedef __attribute__((address_space(3))) unsigned char la_t;
__device__ __forceinline__ void glds16(const void* g, void* l) {
    // async global->LDS, 16B/lane; HW dest = wave-uniform base + lane*16
    __builtin_amdgcn_global_load_lds((ga_t*)g, (la_t*)l, 16, 0, 0);
}

// Pre-pass (r5-verified structure; 16-deep granule swizzle for Q/K)
__global__ __launch_bounds__(256) void prepass_kernel(const float* __restrict__ qkv) {
    __shared__ float lds[64][133];
    const int b = blockIdx.y;
    const int t0 = blockIdx.x * 64;
    const int tid = threadIdx.x;
    const int u = tid >> 3;
    const int j = tid & 7;

    for (int part = 0; part < 2; ++part) {
        // log2(e)/sqrt(128) folded into Q -> attn softmax in exp2 domain
        const float scale = (part == 0) ? 0.127517451f : 1.0f;
        float4 fa[4][2];
#pragma unroll
        for (int i = 0; i < 4; i++) {
            const float* src = qkv + ((size_t)(b * NCH + part * CC + i * 32 + u)) * TT + t0 + j * 8;
            fa[i][0] = *(const float4*)src;
            fa[i][1] = *(const float4*)(src + 4);
        }
        if (part) __syncthreads();
#pragma unroll
        for (int i = 0; i < 4; i++) {
            int c = i * 32 + u;
#pragma unroll
            for (int q = 0; q < 2; q++) {
                lds[j * 8 + q * 4 + 0][c] = fa[i][q].x;
                lds[j * 8 + q * 4 + 1][c] = fa[i][q].y;
                lds[j * 8 + q * 4 + 2][c] = fa[i][q].z;
                lds[j * 8 + q * 4 + 3][c] = fa[i][q].w;
            }
        }
        __syncthreads();
        ushort* dst = (part == 0 ? g_q : g_k) + ((size_t)(b * TT + t0)) * CC;
#pragma unroll
        for (int p = 0; p < 4; p++) {
            int t = p * 16 + (tid >> 4);
            int x = tid & 15;
            int cb = x ^ (t & 15); // 16-deep XOR swizzle baked into ws layout
            ushort tmp[8];
#pragma unroll
            for (int jj = 0; jj < 8; jj++) tmp[jj] = f2bf(lds[t][cb * 8 + jj] * scale);
            *(uint4*)(dst + (size_t)t * CC + x * 8) = *(uint4*)tmp;
        }
    }
    // V: dest-linear; source t-granule permuted (sb = db ^ (c&7)) within 64-groups
    {
        const float* vsrc = qkv + ((size_t)(b * NCH + 2 * CC)) * TT + t0;
        ushort* vdst = g_v + ((size_t)(b * CC)) * TT + t0;
#pragma unroll
        for (int i = 0; i < 4; i++) {
            int idx = i * 256 + tid;
            int c = idx >> 3, db = idx & 7, sb = db ^ (c & 7);
            const float* s = vsrc + (size_t)c * TT + sb * 8;
            float4 f0 = *(const float4*)s;
            float4 f1 = *(const float4*)(s + 4);
            ushort tmp[8] = {f2bf(f0.x), f2bf(f0.y), f2bf(f0.z), f2bf(f0.w),
                             f2bf(f1.x), f2bf(f1.y), f2bf(f1.z), f2bf(f1.w)};
            *(uint4*)(vdst + (size_t)c * TT + db * 8) = *(uint4*)tmp;
        }
    }
}

// Flash attention v3: 32x32x16 MFMA, q-tile 128 (4 waves x 32q), kv-tile 64,
// global_load_lds staging (no ds_writes), double-buffered K/V (2-phase),
// P fully in-register (cvt_pk + shfl_xor(32) lane exchange).
// S^T = K^T*Q: C col = own q = lane&31, rows kt. O^T = V*P: rows c, col q.
__global__ __launch_bounds__(256) void attn_kernel(float* __restrict__ out) {
    __shared__ ushort smem[32768]; // 64KB: 2 x (Ks 64x128 | Vs 128x64); Q aliases buf1

    const int b = blockIdx.y;
    const int q0 = blockIdx.x * 128;
    const int tid = threadIdx.x;
    const int w = tid >> 6;
    const int l = tid & 63;
    const int l31 = l & 31;
    const int hi = l >> 5;
    const int qrow = w * 32 + l31; // local q row owned by this lane (C col)

    const ushort* gq = g_q + ((size_t)(b * TT + q0)) * CC;
    const ushort* gk = g_k + ((size_t)b * TT) * CC;
    const ushort* gv = g_v + ((size_t)b * CC) * TT;

    // ---- stage Q (32KB -> buf1 region) and first K/V tile (-> buf0), async
#pragma unroll
    for (int j = 0; j < 8; j++) {
        int inst = 8 * w + j;
        const ushort* src = gq + (size_t)(4 * inst + (l >> 4)) * CC + (l & 15) * 8;
        glds16(src, smem + 16384 + inst * 512 + l * 8);
    }
    auto stage_kv = [&](int bufoff, int kt0) {
#pragma unroll
        for (int j = 0; j < 4; j++) { // K tile: [64][128] linear
            int inst = 4 * w + j;
            const ushort* src = gk + (size_t)(kt0 + 4 * inst + (l >> 4)) * CC + (l & 15) * 8;
            glds16(src, smem + bufoff + inst * 512 + l * 8);
        }
#pragma unroll
        for (int j = 0; j < 4; j++) { // V tile: [128][64] linear (swizzle pre-baked)
            int inst = 4 * w + j;
            const ushort* src = gv + (size_t)(8 * inst + (l >> 3)) * TT + kt0 + (l & 7) * 8;
            glds16(src, smem + bufoff + 8192 + inst * 512 + l * 8);
        }
    };
    stage_kv(0, 0);
    __syncthreads(); // drains vmcnt: Q + KV(0) ready

    // Q fragments to registers: qf[ck] = Q[qrow][16ck + 8hi .. +8]
    short8 qf[8];
#pragma unroll
    for (int ck = 0; ck < 8; ck++) {
        int x = (2 * ck + hi) ^ (qrow & 15);
        qf[ck] = *(const short8*)(smem + 16384 + qrow * 128 + x * 8);
    }
    __syncthreads(); // all Q reads done before buf1 is re-staged

    floatx16 oacc[4];
#pragma unroll
    for (int cm = 0; cm < 4; cm++)
#pragma unroll
        for (int r = 0; r < 16; r++) oacc[cm][r] = 0.f;
    float m_run = -INFINITY;
    float l_run = 0.f;

    auto compute = [&](int bufoff) {
        const ushort* Ksb = smem + bufoff;
        const ushort* Vsb = smem + bufoff + 8192;

        // S^T: two 32x32 tiles (kt halves), contraction 8 x K=16
        floatx16 sacc[2];
#pragma unroll
        for (int th = 0; th < 2; th++)
#pragma unroll
            for (int r = 0; r < 16; r++) sacc[th][r] = 0.f;
#pragma unroll
        for (int ck = 0; ck < 8; ck++)
#pragma unroll
            for (int th = 0; th < 2; th++) {
                int kt = 32 * th + l31;
                int x = (2 * ck + hi) ^ (kt & 15);
                short8 ak = *(const short8*)(Ksb + kt * 128 + x * 8);
                sacc[th] = __builtin_amdgcn_mfma_f32_32x32x16_bf16(ak, qf[ck], sacc[th], 0, 0, 0);
            }

        // online softmax: lane owns q col; partner (l^32) has the other 16 kt's
        float vmax = -INFINITY;
#pragma unroll
        for (int th = 0; th < 2; th++)
#pragma unroll
            for (int r = 0; r < 16; r++) vmax = fmaxf(vmax, sacc[th][r]);
        vmax = fmaxf(vmax, __shfl_xor(vmax, 32));
        if (!__all(vmax <= m_run + 8.0f)) { // defer-max
            float mnew = fmaxf(m_run, vmax);
            float alpha = exp2f(m_run - mnew);
            l_run *= alpha;
#pragma unroll
            for (int cm = 0; cm < 4; cm++) oacc[cm] = oacc[cm] * alpha;
            m_run = mnew;
        }
        // P in-place into sacc (register pressure)
        float rs = 0.f;
#pragma unroll
        for (int th = 0; th < 2; th++)
#pragma unroll
            for (int r = 0; r < 16; r++) {
                sacc[th][r] = exp2f(sacc[th][r] - m_run);
                rs += sacc[th][r];
            }
        rs += __shfl_xor(rs, 32);
        l_run += rs;

        // pack P to bf16 pairs; exchange halves with partner lane (same q col)
        uint own[2][8], xch[2][8];
#pragma unroll
        for (int th = 0; th < 2; th++)
#pragma unroll
            for (int q8 = 0; q8 < 8; q8++) {
                __hip_bfloat162 h = __float22bfloat162_rn(
                    make_float2(sacc[th][2 * q8], sacc[th][2 * q8 + 1]));
                own[th][q8] = *(uint*)&h;
                xch[th][q8] = __shfl_xor(own[th][q8], 32);
            }

        // PV: O^T += V * P, kt-blocks of 16; B-frag assembled per kt-block
#pragma unroll
        for (int kbg = 0; kbg < 4; kbg++) {
            int th = kbg >> 1, kb = kbg & 1;
            union { uint u[4]; short8 s; } bu;
            bu.u[0] = hi ? xch[th][4 * kb + 2] : own[th][4 * kb + 0];
            bu.u[1] = hi ? xch[th][4 * kb + 3] : own[th][4 * kb + 1];
            bu.u[2] = hi ? own[th][4 * kb + 2] : xch[th][4 * kb + 0];
            bu.u[3] = hi ? own[th][4 * kb + 3] : xch[th][4 * kb + 1];
#pragma unroll
            for (int cm = 0; cm < 4; cm++) {
                int c = 32 * cm + l31;
                int pos = (2 * kbg + hi) ^ (c & 7);
                short8 av = *(const short8*)(Vsb + c * 64 + pos * 8);
                oacc[cm] = __builtin_amdgcn_mfma_f32_32x32x16_bf16(av, bu.s, oacc[cm], 0, 0, 0);
            }
        }
    };

    // 2-phase pipeline: stage(next) issued before compute(cur); barrier drains
#pragma unroll 1
    for (int t = 0; t < 32; t += 2) {
        if (t + 1 < 32) stage_kv(16384, (t + 1) * 64);
        compute(0);
        __syncthreads();
        if (t + 2 < 32) stage_kv(0, (t + 2) * 64);
        compute(16384);
        __syncthreads();
    }

    // epilogue: out[b][c][q0 + qrow] = O^T / l_run
    float inv = 1.0f / l_run;
    float* op = out + ((size_t)b * CC) * TT + q0 + w * 32 + l31;
#pragma unroll
    for (int cm = 0; cm < 4; cm++)
#pragma unroll
        for (int r = 0; r < 16; r++) {
            int c = 32 * cm + (r & 3) + 8 * (r >> 2) + 4 * hi;
            op[(size_t)c * TT] = oacc[cm][r] * inv;
        }
}

extern "C" void kernel_launch(void* const* d_in, const int* in_sizes, int n_in,
                              void* d_out, int out_size, void* d_ws, size_t ws_size,
                              hipStream_t stream) {
    (void)in_sizes; (void)n_in; (void)d_ws; (void)ws_size; (void)out_size;
    const float* qkv = (const float*)d_in[0];
    float* out = (float*)d_out;
    hipLaunchKernelGGL(prepass_kernel, dim3(32, 32), dim3(256), 0, stream, qkv);
    hipLaunchKernelGGL(attn_kernel, dim3(16, 32), dim3(256), 0, stream, out);
}

// Round 9
// 265.013 us; speedup vs baseline: 1.1634x; 1.0983x over previous
//
#include <hip/hip_runtime.h>
#include <hip/hip_bf16.h>
#include <math.h>

#define BB 32
#define CC 128
#define TT 2048
#define NCH 384

typedef __attribute__((ext_vector_type(8))) short short8;
typedef __attribute__((ext_vector_type(16))) float floatx16;

// Static workspace (bf16 bit-patterns). Fully rewritten every call.
__device__ ushort g_q[(size_t)BB * TT * CC]; // [b][t][c granule x = cb ^ (t&15)], Q*scale*log2e
__device__ ushort g_k[(size_t)BB * TT * CC]; // [b][t][c granule x = cb ^ (t&15)]
__device__ ushort g_v[(size_t)BB * CC * TT]; // [b][c][t granule swizzled within 32-groups]

__device__ __forceinline__ ushort f2bf(float f) {
    uint u = __float_as_uint(f);
    u += 0x7fffu + ((u >> 16) & 1u); // RNE
    return (ushort)(u >> 16);
}

typedef __attribute__((address_space(1))) const unsigned char ga_t;
typedef __attribute__((address_space(3))) unsigned char la_t;
__device__ __forceinline__ void glds16(const void* g, void* l) {
    // async global->LDS, 16B/lane; HW dest = wave-uniform base + lane*16
    __builtin_amdgcn_global_load_lds((ga_t*)g, (la_t*)l, 16, 0, 0);
}

// Pre-pass: coalesced loads, LDS f32 transpose, swizzles baked into ws layout.
__global__ __launch_bounds__(256) void prepass_kernel(const float* __restrict__ qkv) {
    __shared__ float lds[64][133];
    const int b = blockIdx.y;
    const int t0 = blockIdx.x * 64;
    const int tid = threadIdx.x;
    const int u = tid >> 3;
    const int j = tid & 7;

    for (int part = 0; part < 2; ++part) {
        // log2(e)/sqrt(128) folded into Q -> attn softmax in exp2 domain
        const float scale = (part == 0) ? 0.127517451f : 1.0f;
        float4 fa[4][2];
#pragma unroll
        for (int i = 0; i < 4; i++) {
            const float* src = qkv + ((size_t)(b * NCH + part * CC + i * 32 + u)) * TT + t0 + j * 8;
            fa[i][0] = *(const float4*)src;
            fa[i][1] = *(const float4*)(src + 4);
        }
        if (part) __syncthreads();
#pragma unroll
        for (int i = 0; i < 4; i++) {
            int c = i * 32 + u;
#pragma unroll
            for (int q = 0; q < 2; q++) {
                lds[j * 8 + q * 4 + 0][c] = fa[i][q].x;
                lds[j * 8 + q * 4 + 1][c] = fa[i][q].y;
                lds[j * 8 + q * 4 + 2][c] = fa[i][q].z;
                lds[j * 8 + q * 4 + 3][c] = fa[i][q].w;
            }
        }
        __syncthreads();
        ushort* dst = (part == 0 ? g_q : g_k) + ((size_t)(b * TT + t0)) * CC;
#pragma unroll
        for (int p = 0; p < 4; p++) {
            int t = p * 16 + (tid >> 4);
            int x = tid & 15;
            int cb = x ^ (t & 15); // 16-deep XOR swizzle baked into ws layout
            ushort tmp[8];
#pragma unroll
            for (int jj = 0; jj < 8; jj++) tmp[jj] = f2bf(lds[t][cb * 8 + jj] * scale);
            *(uint4*)(dst + (size_t)t * CC + x * 8) = *(uint4*)tmp;
        }
    }
    // V: dest-linear; source granule permuted within 32-t-groups:
    // dest granule db holds source sb = (db&4) | ((db ^ c) & 3)
    {
        const float* vsrc = qkv + ((size_t)(b * NCH + 2 * CC)) * TT + t0;
        ushort* vdst = g_v + ((size_t)(b * CC)) * TT + t0;
#pragma unroll
        for (int i = 0; i < 4; i++) {
            int idx = i * 256 + tid;
            int c = idx >> 3, db = idx & 7;
            int sb = (db & 4) | ((db ^ c) & 3);
            const float* s = vsrc + (size_t)c * TT + sb * 8;
            float4 f0 = *(const float4*)s;
            float4 f1 = *(const float4*)(s + 4);
            ushort tmp[8] = {f2bf(f0.x), f2bf(f0.y), f2bf(f0.z), f2bf(f0.w),
                             f2bf(f1.x), f2bf(f1.y), f2bf(f1.z), f2bf(f1.w)};
            *(uint4*)(vdst + (size_t)c * TT + db * 8) = *(uint4*)tmp;
        }
    }
}

// Flash attention v4: 32x32x16 MFMA, q-tile 128 (4 waves x 32q), kv-tile 32,
// LDS 32KB (double-buffered K/V), Q direct global->reg, in-register P.
// S^T = K^T*Q: C col = own q = lane&31, rows kt. O^T = V*P: rows c, col q.
__global__ __launch_bounds__(256, 3) void attn_kernel(float* __restrict__ out) {
    __shared__ ushort smem[16384]; // 32KB: 2 x (K 32x128 | V 128x32)

    const int b = blockIdx.y;
    const int q0 = blockIdx.x * 128;
    const int tid = threadIdx.x;
    const int w = tid >> 6;
    const int l = tid & 63;
    const int l31 = l & 31;
    const int hi = l >> 5;
    const int qrow = w * 32 + l31; // local q row owned by this lane (C col)

    const ushort* gq = g_q + ((size_t)(b * TT + q0)) * CC;
    const ushort* gk = g_k + ((size_t)b * TT) * CC;
    const ushort* gv = g_v + ((size_t)b * CC) * TT;

    // Q fragments straight from global (one-time): qf[ck] = Q[qrow][16ck+8hi..]
    short8 qf[8];
#pragma unroll
    for (int ck = 0; ck < 8; ck++) {
        int x = (2 * ck + hi) ^ (qrow & 15);
        qf[ck] = *(const short8*)(gq + (size_t)qrow * CC + x * 8);
    }

    auto stage_kv = [&](int off, int kt0) {
#pragma unroll
        for (int j = 0; j < 2; j++) { // K tile [32][128]: 8 x 1KB instrs
            int inst = 2 * w + j;
            const ushort* src = gk + (size_t)(kt0 + 4 * inst + (l >> 4)) * CC + (l & 15) * 8;
            glds16(src, smem + off + inst * 512 + l * 8);
        }
#pragma unroll
        for (int j = 0; j < 2; j++) { // V tile [128][32]: 8 x 1KB instrs
            int inst = 2 * w + j;
            const ushort* src = gv + (size_t)(16 * inst + (l >> 2)) * TT + kt0 + (l & 3) * 8;
            glds16(src, smem + off + 4096 + inst * 512 + l * 8);
        }
    };
    stage_kv(0, 0);
    stage_kv(8192, 32);
    __syncthreads(); // drain: both initial tiles ready

    floatx16 oacc[4];
#pragma unroll
    for (int cm = 0; cm < 4; cm++)
#pragma unroll
        for (int r = 0; r < 16; r++) oacc[cm][r] = 0.f;
    float m_run = -INFINITY;
    float l_run = 0.f;

    auto compute = [&](int off) {
        const ushort* Ksb = smem + off;
        const ushort* Vsb = smem + off + 4096;

        // S^T: one 32x32 tile, contraction 8 x K=16
        floatx16 sacc;
#pragma unroll
        for (int r = 0; r < 16; r++) sacc[r] = 0.f;
#pragma unroll
        for (int ck = 0; ck < 8; ck++) {
            int x = (2 * ck + hi) ^ (l31 & 15);
            short8 ak = *(const short8*)(Ksb + l31 * 128 + x * 8);
            sacc = __builtin_amdgcn_mfma_f32_32x32x16_bf16(ak, qf[ck], sacc, 0, 0, 0);
        }

        // online softmax: lane owns q col; partner (l^32) has the other 16 kt
        float vmax = -INFINITY;
#pragma unroll
        for (int r = 0; r < 16; r++) vmax = fmaxf(vmax, sacc[r]);
        vmax = fmaxf(vmax, __shfl_xor(vmax, 32));
        if (!__all(vmax <= m_run + 8.0f)) { // defer-max
            float mnew = fmaxf(m_run, vmax);
            float alpha = exp2f(m_run - mnew);
            l_run *= alpha;
#pragma unroll
            for (int cm = 0; cm < 4; cm++) oacc[cm] = oacc[cm] * alpha;
            m_run = mnew;
        }
        float rs = 0.f;
#pragma unroll
        for (int r = 0; r < 16; r++) {
            sacc[r] = exp2f(sacc[r] - m_run);
            rs += sacc[r];
        }
        rs += __shfl_xor(rs, 32);
        l_run += rs;

        // pack P to bf16 pairs; exchange halves with partner lane (same q col)
        uint own[8], xch[8];
#pragma unroll
        for (int q8 = 0; q8 < 8; q8++) {
            __hip_bfloat162 h = __float22bfloat162_rn(
                make_float2(sacc[2 * q8], sacc[2 * q8 + 1]));
            own[q8] = *(uint*)&h;
            xch[q8] = __shfl_xor(own[q8], 32);
        }

        // PV: O^T += V * P, two kt-blocks of 16
#pragma unroll
        for (int kb = 0; kb < 2; kb++) {
            union { uint u[4]; short8 s; } bu;
            bu.u[0] = hi ? xch[4 * kb + 2] : own[4 * kb + 0];
            bu.u[1] = hi ? xch[4 * kb + 3] : own[4 * kb + 1];
            bu.u[2] = hi ? own[4 * kb + 2] : xch[4 * kb + 0];
            bu.u[3] = hi ? own[4 * kb + 3] : xch[4 * kb + 1];
#pragma unroll
            for (int cm = 0; cm < 4; cm++) {
                int c = 32 * cm + l31;
                int pos = (2 * kb + hi) ^ (c & 3);
                short8 av = *(const short8*)(Vsb + c * 32 + pos * 8);
                oacc[cm] = __builtin_amdgcn_mfma_f32_32x32x16_bf16(av, bu.s, oacc[cm], 0, 0, 0);
            }
        }
    };

    // 64 kv-steps of 32; dbuf: stage(t+2) issued after the barrier that ends
    // reads of that buffer; completion guaranteed by the NEXT barrier's drain.
#pragma unroll 1
    for (int t = 0; t < 64; t += 2) {
        compute(0);
        __syncthreads();
        if (t + 2 < 64) stage_kv(0, (t + 2) * 32);
        compute(8192);
        __syncthreads();
        if (t + 3 < 64) stage_kv(8192, (t + 3) * 32);
    }

    // epilogue: out[b][c][q0 + qrow] = O^T / l_run
    float inv = 1.0f / l_run;
    float* op = out + ((size_t)b * CC) * TT + q0 + qrow;
#pragma unroll
    for (int cm = 0; cm < 4; cm++)
#pragma unroll
        for (int r = 0; r < 16; r++) {
            int c = 32 * cm + (r & 3) + 8 * (r >> 2) + 4 * hi;
            op[(size_t)c * TT] = oacc[cm][r] * inv;
        }
}

extern "C" void kernel_launch(void* const* d_in, const int* in_sizes, int n_in,
                              void* d_out, int out_size, void* d_ws, size_t ws_size,
                              hipStream_t stream) {
    (void)in_sizes; (void)n_in; (void)d_ws; (void)ws_size; (void)out_size;
    const float* qkv = (const float*)d_in[0];
    float* out = (float*)d_out;
    hipLaunchKernelGGL(prepass_kernel, dim3(32, 32), dim3(256), 0, stream, qkv);
    hipLaunchKernelGGL(attn_kernel, dim3(16, 32), dim3(256), 0, stream, out);
}